// Round 1
// baseline (6129.106 us; speedup 1.0000x reference)
//
#include <hip/hip_runtime.h>
#include <hip/hip_bf16.h>
#include <cstddef>

#define N_NODES 16000
#define N_EDGES 256000
#define DIM 256
#define HEADS 8
#define DFF 1024
#define LN_EPS 1e-5f
#define CNT ((float)((size_t)N_NODES * DIM))

__device__ __forceinline__ float bf2f(unsigned int s) {
    return __uint_as_float(s << 16);
}

// ---------------- fp32 tiled GEMM: C[M,N] = A[M,K] @ B[K,N] (+bias)(+relu)(+res) ---
// BM=BN=64, BK=16, 256 threads, 4x4 per thread. M%64==0, N%64==0, K%16==0 assumed.
template<int BIAS, int RELU, int RES, int OBF16>
__global__ __launch_bounds__(256) void gemm_k(
    const float* __restrict__ A, const float* __restrict__ B,
    const float* __restrict__ bias, const float* __restrict__ res,
    void* __restrict__ C, int M, int K, int N)
{
    __shared__ float As[16][68];   // [k][m], padded row stride 68 (16B aligned, conflict-safe)
    __shared__ float Bs[16][64];   // [k][n]
    const int tid = threadIdx.x;
    const int tx = tid & 15, ty = tid >> 4;
    const int row0 = blockIdx.y * 64, col0 = blockIdx.x * 64;
    // A loader: thread -> row ar (0..63), k-quad ak
    const int ar = tid >> 2;
    const int ak = (tid & 3) * 4;
    // B loader: thread -> k row bk (0..15), col-quad bc
    const int bc = (tid & 15) * 4;
    const int bk = tid >> 4;
    float acc[4][4] = {};
    for (int k0 = 0; k0 < K; k0 += 16) {
        float4 av = *(const float4*)(A + (size_t)(row0 + ar) * K + k0 + ak);
        As[ak + 0][ar] = av.x;
        As[ak + 1][ar] = av.y;
        As[ak + 2][ar] = av.z;
        As[ak + 3][ar] = av.w;
        *(float4*)&Bs[bk][bc] = *(const float4*)(B + (size_t)(k0 + bk) * N + col0 + bc);
        __syncthreads();
        #pragma unroll
        for (int kk = 0; kk < 16; kk++) {
            float4 a4 = *(const float4*)&As[kk][ty * 4];
            float4 b4 = *(const float4*)&Bs[kk][tx * 4];
            float a[4] = {a4.x, a4.y, a4.z, a4.w};
            float b[4] = {b4.x, b4.y, b4.z, b4.w};
            #pragma unroll
            for (int i = 0; i < 4; i++)
                #pragma unroll
                for (int j = 0; j < 4; j++)
                    acc[i][j] = fmaf(a[i], b[j], acc[i][j]);
        }
        __syncthreads();
    }
    #pragma unroll
    for (int i = 0; i < 4; i++) {
        int r = row0 + ty * 4 + i;
        #pragma unroll
        for (int j = 0; j < 4; j++) {
            int c = col0 + tx * 4 + j;
            float v = acc[i][j];
            if (BIAS) v += bias[c];
            if (RELU) v = fmaxf(v, 0.0f);
            if (RES)  v += res[(size_t)r * N + c];
            if (OBF16) ((__hip_bfloat16*)C)[(size_t)r * N + c] = __float2bfloat16(v);
            else       ((float*)C)[(size_t)r * N + c] = v;
        }
    }
}

// ---------------- edge pass: one wave per edge ----------------
// alpha_h = (q[dst] . (K[src]+e))_h * invdist/sqrt(32); ex = exp(alpha)
// denom[dst,h] += ex ; out[dst,c] += ex * (V[src,c]+e_c)   (normalize later)
__global__ __launch_bounds__(256) void edge_pass_k(
    const float* __restrict__ Q, const float* __restrict__ Kn,
    const float* __restrict__ Vn, const __hip_bfloat16* __restrict__ Ep,
    const int* __restrict__ src, const int* __restrict__ dst,
    const float* __restrict__ x_dist,
    float* __restrict__ outb, float* __restrict__ denom)
{
    const int lane = threadIdx.x & 63;
    int wid = (blockIdx.x * blockDim.x + threadIdx.x) >> 6;
    const int nw = (gridDim.x * blockDim.x) >> 6;
    const float rsdh = 0.17677669529663687f;  // 1/sqrt(32)
    for (int e = wid; e < N_EDGES; e += nw) {
        const int s = src[e], d = dst[e];
        const float4 q  = *(const float4*)(Q  + (size_t)d * DIM + lane * 4);
        const float4 kv = *(const float4*)(Kn + (size_t)s * DIM + lane * 4);
        const float4 vv = *(const float4*)(Vn + (size_t)s * DIM + lane * 4);
        uint2 eb = *(const uint2*)(Ep + (size_t)e * DIM + lane * 4);
        float e0 = bf2f(eb.x & 0xffffu), e1 = bf2f(eb.x >> 16);
        float e2 = bf2f(eb.y & 0xffffu), e3 = bf2f(eb.y >> 16);
        float part = q.x * (kv.x + e0) + q.y * (kv.y + e1)
                   + q.z * (kv.z + e2) + q.w * (kv.w + e3);
        // reduce over the 8 lanes of this head (32 channels)
        part += __shfl_xor(part, 1);
        part += __shfl_xor(part, 2);
        part += __shfl_xor(part, 4);
        float invd = 1.0f / x_dist[e];
        float ex = __expf(part * invd * rsdh);
        if ((lane & 7) == 0) atomicAdd(&denom[(size_t)d * HEADS + (lane >> 3)], ex);
        float* ob = outb + (size_t)d * DIM + lane * 4;
        atomicAdd(ob + 0, (vv.x + e0) * ex);
        atomicAdd(ob + 1, (vv.y + e1) * ex);
        atomicAdd(ob + 2, (vv.z + e2) * ex);
        atomicAdd(ob + 3, (vv.w + e3) * ex);
    }
}

// ---------------- node finish: y = x + out/denom + skip ----------------
__global__ __launch_bounds__(256) void node_finish_k(
    const float* __restrict__ x, const float* __restrict__ outb,
    const float* __restrict__ denom, const float* __restrict__ S,
    float* __restrict__ y)
{
    int idx = blockIdx.x * blockDim.x + threadIdx.x;
    if (idx >= N_NODES * DIM) return;
    int n = idx >> 8, c = idx & 255;
    float dn = denom[(size_t)n * HEADS + (c >> 5)] + 1e-16f;
    y[idx] = x[idx] + outb[idx] / dn + S[idx];
}

// ---------------- LN stats: global sum / sumsq via block partials ----------------
__global__ __launch_bounds__(256) void stats_k(const float* __restrict__ y, float* __restrict__ stats)
{
    int idx = blockIdx.x * blockDim.x + threadIdx.x;  // float4 index
    float4 v = *(const float4*)(y + (size_t)idx * 4);
    float s = v.x + v.y + v.z + v.w;
    float ss = v.x * v.x + v.y * v.y + v.z * v.z + v.w * v.w;
    #pragma unroll
    for (int o = 32; o > 0; o >>= 1) {
        s  += __shfl_down(s, o);
        ss += __shfl_down(ss, o);
    }
    __shared__ float ls[4], lss[4];
    int w = threadIdx.x >> 6, ln = threadIdx.x & 63;
    if (ln == 0) { ls[w] = s; lss[w] = ss; }
    __syncthreads();
    if (threadIdx.x == 0) {
        atomicAdd(&stats[0], ls[0] + ls[1] + ls[2] + ls[3]);
        atomicAdd(&stats[1], lss[0] + lss[1] + lss[2] + lss[3]);
    }
}

// ---------------- LN apply: x = (y-mu)/(std+eps)*g + b ----------------
__global__ __launch_bounds__(256) void apply_k(
    const float* __restrict__ y, const float* __restrict__ stats,
    const float* __restrict__ g, const float* __restrict__ b,
    float* __restrict__ xo)
{
    int idx = blockIdx.x * blockDim.x + threadIdx.x;  // float4 index
    float mu = stats[0] * (1.0f / CNT);
    float var = stats[1] * (1.0f / CNT) - mu * mu;
    float sc = 1.0f / (sqrtf(fmaxf(var, 0.0f)) + LN_EPS);
    int cb = (idx & 63) * 4;   // channel base (DIM=256 -> 64 float4 per row)
    float4 v  = *(const float4*)(y + (size_t)idx * 4);
    float4 gv = *(const float4*)(g + cb);
    float4 bv = *(const float4*)(b + cb);
    float4 o;
    o.x = (v.x - mu) * sc * gv.x + bv.x;
    o.y = (v.y - mu) * sc * gv.y + bv.y;
    o.z = (v.z - mu) * sc * gv.z + bv.z;
    o.w = (v.w - mu) * sc * gv.w + bv.w;
    *(float4*)(xo + (size_t)idx * 4) = o;
}

extern "C" void kernel_launch(void* const* d_in, const int* in_sizes, int n_in,
                              void* d_out, int out_size, void* d_ws, size_t ws_size,
                              hipStream_t stream) {
    const float* x_in   = (const float*)d_in[0];
    const int*   ei     = (const int*)d_in[1];
    const int*   src    = ei;                 // edge_index[0]
    const int*   dstp   = ei + N_EDGES;       // edge_index[1]
    const float* x_edge = (const float*)d_in[2];
    const float* x_dist = (const float*)d_in[3];
    const float* Wq  = (const float*)d_in[4];
    const float* bq  = (const float*)d_in[5];
    const float* Wk  = (const float*)d_in[6];
    const float* bk  = (const float*)d_in[7];
    const float* Wv  = (const float*)d_in[8];
    const float* bv  = (const float*)d_in[9];
    const float* We  = (const float*)d_in[10];
    const float* Wsk = (const float*)d_in[11];
    const float* bsk = (const float*)d_in[12];
    const float* g1  = (const float*)d_in[13];
    const float* b1  = (const float*)d_in[14];
    const float* W1  = (const float*)d_in[15];
    const float* c1  = (const float*)d_in[16];
    const float* W2  = (const float*)d_in[17];
    const float* c2  = (const float*)d_in[18];
    const float* g2  = (const float*)d_in[19];
    const float* b2  = (const float*)d_in[20];

    // ---- workspace carve (~312 MB) ----
    char* p = (char*)d_ws;
    const size_t NB = (size_t)N_NODES * DIM * sizeof(float);   // 16,384,000
    float* xbuf = (float*)p; p += NB;
    float* ybuf = (float*)p; p += NB;
    float* Qb   = (float*)p; p += NB;
    float* Kb   = (float*)p; p += NB;
    float* Vb   = (float*)p; p += NB;
    float* Sb   = (float*)p; p += NB;
    float* hb   = (float*)p; p += (size_t)N_NODES * DFF * sizeof(float);  // 65.5 MB
    __hip_bfloat16* Ep = (__hip_bfloat16*)p; p += (size_t)N_EDGES * DIM * 2;  // 131 MB
    float* stats = (float*)p;                                   // 8 floats: 2 LN slots
    float* denom = (float*)(p + 32);                            // [N,H]
    float* outb  = (float*)(p + 32 + (size_t)N_NODES * HEADS * sizeof(float));
    const size_t zero_bytes = 32 + (size_t)N_NODES * HEADS * sizeof(float) + NB;

    hipMemcpyAsync(xbuf, x_in, NB, hipMemcpyDeviceToDevice, stream);

    const dim3 blk(256);
    const dim3 gnode(DIM / 64, N_NODES / 64);     // (4, 250)
    const dim3 gedge(DIM / 64, N_EDGES / 64);     // (4, 4000) — x-fast shares A tile in L2
    const dim3 gff1(DFF / 64, N_NODES / 64);      // (16, 250)

    for (int i = 0; i < 3; i++) {
        const size_t wo = (size_t)i * DIM * DIM;
        const size_t w1o = (size_t)i * DIM * DFF;
        const size_t bo = (size_t)i * DIM;
        const size_t b1o = (size_t)i * DFF;

        hipMemsetAsync(stats, 0, zero_bytes, stream);   // stats + denom + outb

        // node projections Q,K,V,S
        gemm_k<1,0,0,0><<<gnode, blk, 0, stream>>>(xbuf, Wq + wo, bq + bo, nullptr, Qb, N_NODES, DIM, DIM);
        gemm_k<1,0,0,0><<<gnode, blk, 0, stream>>>(xbuf, Wk + wo, bk + bo, nullptr, Kb, N_NODES, DIM, DIM);
        gemm_k<1,0,0,0><<<gnode, blk, 0, stream>>>(xbuf, Wv + wo, bv + bo, nullptr, Vb, N_NODES, DIM, DIM);
        gemm_k<1,0,0,0><<<gnode, blk, 0, stream>>>(xbuf, Wsk + wo, bsk + bo, nullptr, Sb, N_NODES, DIM, DIM);
        // edge projection (bf16 out)
        gemm_k<0,0,0,1><<<gedge, blk, 0, stream>>>(x_edge, We + wo, nullptr, nullptr, Ep, N_EDGES, DIM, DIM);
        // attention scatter
        edge_pass_k<<<2048, blk, 0, stream>>>(Qb, Kb, Vb, Ep, src, dstp, x_dist, outb, denom);
        // y = x + out/denom + skip ; LN1
        node_finish_k<<<(N_NODES * DIM) / 256, blk, 0, stream>>>(xbuf, outb, denom, Sb, ybuf);
        stats_k<<<(N_NODES * DIM) / 1024, blk, 0, stream>>>(ybuf, stats);
        apply_k<<<(N_NODES * DIM) / 1024, blk, 0, stream>>>(ybuf, stats, g1 + bo, b1 + bo, xbuf);
        // FFN
        gemm_k<1,1,0,0><<<gff1, blk, 0, stream>>>(xbuf, W1 + w1o, c1 + b1o, nullptr, hb, N_NODES, DIM, DFF);
        gemm_k<1,0,1,0><<<gnode, blk, 0, stream>>>(hb, W2 + w1o, c2 + bo, xbuf, ybuf, N_NODES, DFF, DIM);
        stats_k<<<(N_NODES * DIM) / 1024, blk, 0, stream>>>(ybuf, stats + 2);
        float* xdst = (i == 2) ? (float*)d_out : xbuf;
        apply_k<<<(N_NODES * DIM) / 1024, blk, 0, stream>>>(ybuf, stats + 2, g2 + bo, b2 + bo, xdst);
    }
}

// Round 2
// 3879.490 us; speedup vs baseline: 1.5799x; 1.5799x over previous
//
#include <hip/hip_runtime.h>
#include <hip/hip_bf16.h>
#include <cstddef>

#define N_NODES 16000
#define N_EDGES 256000
#define DIM 256
#define HEADS 8
#define DFF 1024
#define LN_EPS 1e-5f
#define CNT ((float)((size_t)N_NODES * DIM))

__device__ __forceinline__ float bf2f(unsigned int s) {
    return __uint_as_float(s << 16);
}

// ---------------- fp32 tiled GEMM: C[M,N] = A[M,K] @ B[K,N] (+bias)(+relu)(+res) ---
// BM=BN=64, BK=16, 256 threads, 4x4 per thread. M%64==0, N%64==0, K%16==0 assumed.
template<int BIAS, int RELU, int RES, int OBF16>
__global__ __launch_bounds__(256) void gemm_k(
    const float* __restrict__ A, const float* __restrict__ B,
    const float* __restrict__ bias, const float* __restrict__ res,
    void* __restrict__ C, int M, int K, int N)
{
    __shared__ float As[16][68];   // [k][m], padded
    __shared__ float Bs[16][64];   // [k][n]
    const int tid = threadIdx.x;
    const int tx = tid & 15, ty = tid >> 4;
    const int row0 = blockIdx.y * 64, col0 = blockIdx.x * 64;
    const int ar = tid >> 2;
    const int ak = (tid & 3) * 4;
    const int bc = (tid & 15) * 4;
    const int bk = tid >> 4;
    float acc[4][4] = {};
    for (int k0 = 0; k0 < K; k0 += 16) {
        float4 av = *(const float4*)(A + (size_t)(row0 + ar) * K + k0 + ak);
        As[ak + 0][ar] = av.x;
        As[ak + 1][ar] = av.y;
        As[ak + 2][ar] = av.z;
        As[ak + 3][ar] = av.w;
        *(float4*)&Bs[bk][bc] = *(const float4*)(B + (size_t)(k0 + bk) * N + col0 + bc);
        __syncthreads();
        #pragma unroll
        for (int kk = 0; kk < 16; kk++) {
            float4 a4 = *(const float4*)&As[kk][ty * 4];
            float4 b4 = *(const float4*)&Bs[kk][tx * 4];
            float a[4] = {a4.x, a4.y, a4.z, a4.w};
            float b[4] = {b4.x, b4.y, b4.z, b4.w};
            #pragma unroll
            for (int i = 0; i < 4; i++)
                #pragma unroll
                for (int j = 0; j < 4; j++)
                    acc[i][j] = fmaf(a[i], b[j], acc[i][j]);
        }
        __syncthreads();
    }
    #pragma unroll
    for (int i = 0; i < 4; i++) {
        int r = row0 + ty * 4 + i;
        #pragma unroll
        for (int j = 0; j < 4; j++) {
            int c = col0 + tx * 4 + j;
            float v = acc[i][j];
            if (BIAS) v += bias[c];
            if (RELU) v = fmaxf(v, 0.0f);
            if (RES)  v += res[(size_t)r * N + c];
            if (OBF16) ((__hip_bfloat16*)C)[(size_t)r * N + c] = __float2bfloat16(v);
            else       ((float*)C)[(size_t)r * N + c] = v;
        }
    }
}

// ---------------- CSR build: histogram -> scan -> scatter ----------------
__global__ __launch_bounds__(256) void hist_k(const int* __restrict__ dst, int* __restrict__ deg)
{
    int e = blockIdx.x * blockDim.x + threadIdx.x;
    if (e < N_EDGES) atomicAdd(&deg[dst[e]], 1);
}

__global__ __launch_bounds__(1024) void scan_k(const int* __restrict__ deg,
                                               int* __restrict__ rowptr,
                                               int* __restrict__ cursor)
{
    __shared__ int wsum[16];
    const int t = threadIdx.x;          // 16000 = 1000 threads x 16
    const int base = t * 16;
    int local[16];
    int s = 0;
    if (t < 1000) {
        #pragma unroll
        for (int j = 0; j < 16; j++) { local[j] = s; s += deg[base + j]; }
    }
    const int lane = t & 63, w = t >> 6;
    int v = s;
    #pragma unroll
    for (int off = 1; off < 64; off <<= 1) {
        int u = __shfl_up(v, off);
        if (lane >= off) v += u;
    }
    if (lane == 63) wsum[w] = v;
    __syncthreads();
    if (t == 0) {
        int r = 0;
        #pragma unroll
        for (int i = 0; i < 16; i++) { int u = wsum[i]; wsum[i] = r; r += u; }
    }
    __syncthreads();
    const int excl = v - s + wsum[w];
    if (t < 1000) {
        #pragma unroll
        for (int j = 0; j < 16; j++) {
            rowptr[base + j] = excl + local[j];
            cursor[base + j] = excl + local[j];
        }
        if (t == 999) rowptr[16000] = excl + s;
    }
}

__global__ __launch_bounds__(256) void scatter_k(const int* __restrict__ dst,
                                                 int* __restrict__ cursor,
                                                 int* __restrict__ eperm)
{
    int e = blockIdx.x * blockDim.x + threadIdx.x;
    if (e < N_EDGES) {
        int pos = atomicAdd(&cursor[dst[e]], 1);
        eperm[pos] = e;
    }
}

// ---------------- per-node attention aggregation (one wave per dst node) --------
// For node n, walk its incoming edges: alpha_h = q.(k+e)_h * invd/sqrt(32),
// ex = exp(alpha) (x is LN'ed, |alpha| small -> no overflow; max-shift is a no-op
// in the softmax ratio). Accumulate denom per head and ex*(v+e) per channel in
// registers, then write y = x + acc/denom + skip once. No atomics.
__global__ __launch_bounds__(256) void node_agg_k(
    const float* __restrict__ Q, const float* __restrict__ Kn,
    const float* __restrict__ Vn, const __hip_bfloat16* __restrict__ Ep,
    const int* __restrict__ src, const float* __restrict__ x_dist,
    const int* __restrict__ rowptr, const int* __restrict__ eperm,
    const float* __restrict__ x, const float* __restrict__ S,
    float* __restrict__ y)
{
    const int lane = threadIdx.x & 63;
    const int n = (blockIdx.x * blockDim.x + threadIdx.x) >> 6;
    if (n >= N_NODES) return;
    const float rsdh = 0.17677669529663687f;  // 1/sqrt(32)
    const float4 q = *(const float4*)(Q + (size_t)n * DIM + lane * 4);
    float a0 = 0, a1 = 0, a2 = 0, a3 = 0, den = 0;
    const int beg = rowptr[n], end = rowptr[n + 1];
    int e = (beg < end) ? eperm[beg] : 0;
    int s = (beg < end) ? src[e] : 0;
    for (int i = beg; i < end; i++) {
        const int ecur = e, scur = s;
        if (i + 1 < end) { e = eperm[i + 1]; s = src[e]; }   // prefetch next gather idx
        const float4 kv = *(const float4*)(Kn + (size_t)scur * DIM + lane * 4);
        const float4 vv = *(const float4*)(Vn + (size_t)scur * DIM + lane * 4);
        const uint2 eb = *(const uint2*)(Ep + (size_t)ecur * DIM + lane * 4);
        const float invd = 1.0f / x_dist[ecur];
        const float e0 = bf2f(eb.x & 0xffffu), e1 = bf2f(eb.x >> 16);
        const float e2 = bf2f(eb.y & 0xffffu), e3 = bf2f(eb.y >> 16);
        float part = q.x * (kv.x + e0) + q.y * (kv.y + e1)
                   + q.z * (kv.z + e2) + q.w * (kv.w + e3);
        part += __shfl_xor(part, 1);
        part += __shfl_xor(part, 2);
        part += __shfl_xor(part, 4);   // all 8 lanes of this head share the dot
        const float ex = __expf(part * invd * rsdh);
        den += ex;
        a0 = fmaf(vv.x + e0, ex, a0);
        a1 = fmaf(vv.y + e1, ex, a1);
        a2 = fmaf(vv.z + e2, ex, a2);
        a3 = fmaf(vv.w + e3, ex, a3);
    }
    const float dn = 1.0f / (den + 1e-16f);
    const size_t o = (size_t)n * DIM + lane * 4;
    const float4 xr = *(const float4*)(x + o);
    const float4 sr = *(const float4*)(S + o);
    float4 out;
    out.x = xr.x + a0 * dn + sr.x;
    out.y = xr.y + a1 * dn + sr.y;
    out.z = xr.z + a2 * dn + sr.z;
    out.w = xr.w + a3 * dn + sr.w;
    *(float4*)(y + o) = out;
}

// ---------------- LN stats: global sum / sumsq via block partials ----------------
__global__ __launch_bounds__(256) void stats_k(const float* __restrict__ y, float* __restrict__ stats)
{
    int idx = blockIdx.x * blockDim.x + threadIdx.x;  // float4 index
    float4 v = *(const float4*)(y + (size_t)idx * 4);
    float s = v.x + v.y + v.z + v.w;
    float ss = v.x * v.x + v.y * v.y + v.z * v.z + v.w * v.w;
    #pragma unroll
    for (int o = 32; o > 0; o >>= 1) {
        s  += __shfl_down(s, o);
        ss += __shfl_down(ss, o);
    }
    __shared__ float ls[4], lss[4];
    int w = threadIdx.x >> 6, ln = threadIdx.x & 63;
    if (ln == 0) { ls[w] = s; lss[w] = ss; }
    __syncthreads();
    if (threadIdx.x == 0) {
        atomicAdd(&stats[0], ls[0] + ls[1] + ls[2] + ls[3]);
        atomicAdd(&stats[1], lss[0] + lss[1] + lss[2] + lss[3]);
    }
}

// ---------------- LN apply: x = (y-mu)/(std+eps)*g + b ----------------
__global__ __launch_bounds__(256) void apply_k(
    const float* __restrict__ y, const float* __restrict__ stats,
    const float* __restrict__ g, const float* __restrict__ b,
    float* __restrict__ xo)
{
    int idx = blockIdx.x * blockDim.x + threadIdx.x;  // float4 index
    float mu = stats[0] * (1.0f / CNT);
    float var = stats[1] * (1.0f / CNT) - mu * mu;
    float sc = 1.0f / (sqrtf(fmaxf(var, 0.0f)) + LN_EPS);
    int cb = (idx & 63) * 4;
    float4 v  = *(const float4*)(y + (size_t)idx * 4);
    float4 gv = *(const float4*)(g + cb);
    float4 bv = *(const float4*)(b + cb);
    float4 o;
    o.x = (v.x - mu) * sc * gv.x + bv.x;
    o.y = (v.y - mu) * sc * gv.y + bv.y;
    o.z = (v.z - mu) * sc * gv.z + bv.z;
    o.w = (v.w - mu) * sc * gv.w + bv.w;
    *(float4*)(xo + (size_t)idx * 4) = o;
}

extern "C" void kernel_launch(void* const* d_in, const int* in_sizes, int n_in,
                              void* d_out, int out_size, void* d_ws, size_t ws_size,
                              hipStream_t stream) {
    const float* x_in   = (const float*)d_in[0];
    const int*   ei     = (const int*)d_in[1];
    const int*   src    = ei;                 // edge_index[0]
    const int*   dstp   = ei + N_EDGES;       // edge_index[1]
    const float* x_edge = (const float*)d_in[2];
    const float* x_dist = (const float*)d_in[3];
    const float* Wq  = (const float*)d_in[4];
    const float* bq  = (const float*)d_in[5];
    const float* Wk  = (const float*)d_in[6];
    const float* bk  = (const float*)d_in[7];
    const float* Wv  = (const float*)d_in[8];
    const float* bv  = (const float*)d_in[9];
    const float* We  = (const float*)d_in[10];
    const float* Wsk = (const float*)d_in[11];
    const float* bsk = (const float*)d_in[12];
    const float* g1  = (const float*)d_in[13];
    const float* b1  = (const float*)d_in[14];
    const float* W1  = (const float*)d_in[15];
    const float* c1  = (const float*)d_in[16];
    const float* W2  = (const float*)d_in[17];
    const float* c2  = (const float*)d_in[18];
    const float* g2  = (const float*)d_in[19];
    const float* b2  = (const float*)d_in[20];

    // ---- workspace carve (~296 MB) ----
    char* p = (char*)d_ws;
    const size_t NB = (size_t)N_NODES * DIM * sizeof(float);   // 16,384,000
    float* xbuf = (float*)p; p += NB;
    float* ybuf = (float*)p; p += NB;
    float* Qb   = (float*)p; p += NB;
    float* Kb   = (float*)p; p += NB;
    float* Vb   = (float*)p; p += NB;
    float* Sb   = (float*)p; p += NB;
    float* hb   = (float*)p; p += (size_t)N_NODES * DFF * sizeof(float);  // 65.5 MB
    __hip_bfloat16* Ep = (__hip_bfloat16*)p; p += (size_t)N_EDGES * DIM * 2;  // 131 MB
    float* stats  = (float*)p; p += 32;
    int* deg      = (int*)p;   p += (size_t)N_NODES * sizeof(int);
    int* rowptr   = (int*)p;   p += (size_t)(N_NODES + 4) * sizeof(int);
    int* cursor   = (int*)p;   p += (size_t)N_NODES * sizeof(int);
    int* eperm    = (int*)p;   p += (size_t)N_EDGES * sizeof(int);

    hipMemcpyAsync(xbuf, x_in, NB, hipMemcpyDeviceToDevice, stream);

    const dim3 blk(256);
    const dim3 gnode(DIM / 64, N_NODES / 64);     // (4, 250)
    const dim3 gedge(DIM / 64, N_EDGES / 64);     // (4, 4000)
    const dim3 gff1(DFF / 64, N_NODES / 64);      // (16, 250)

    // ---- CSR build (edge list is constant across the 3 blocks) ----
    hipMemsetAsync(deg, 0, (size_t)N_NODES * sizeof(int), stream);
    hist_k<<<N_EDGES / 256, blk, 0, stream>>>(dstp, deg);
    scan_k<<<1, 1024, 0, stream>>>(deg, rowptr, cursor);
    scatter_k<<<N_EDGES / 256, blk, 0, stream>>>(dstp, cursor, eperm);

    for (int i = 0; i < 3; i++) {
        const size_t wo = (size_t)i * DIM * DIM;
        const size_t w1o = (size_t)i * DIM * DFF;
        const size_t bo = (size_t)i * DIM;
        const size_t b1o = (size_t)i * DFF;

        hipMemsetAsync(stats, 0, 32, stream);

        // node projections Q,K,V,S
        gemm_k<1,0,0,0><<<gnode, blk, 0, stream>>>(xbuf, Wq + wo, bq + bo, nullptr, Qb, N_NODES, DIM, DIM);
        gemm_k<1,0,0,0><<<gnode, blk, 0, stream>>>(xbuf, Wk + wo, bk + bo, nullptr, Kb, N_NODES, DIM, DIM);
        gemm_k<1,0,0,0><<<gnode, blk, 0, stream>>>(xbuf, Wv + wo, bv + bo, nullptr, Vb, N_NODES, DIM, DIM);
        gemm_k<1,0,0,0><<<gnode, blk, 0, stream>>>(xbuf, Wsk + wo, bsk + bo, nullptr, Sb, N_NODES, DIM, DIM);
        // edge projection (bf16 out)
        gemm_k<0,0,0,1><<<gedge, blk, 0, stream>>>(x_edge, We + wo, nullptr, nullptr, Ep, N_EDGES, DIM, DIM);
        // attention aggregation, fused with residual + skip -> ybuf
        node_agg_k<<<N_NODES / 4, blk, 0, stream>>>(Qb, Kb, Vb, Ep, src, x_dist,
                                                    rowptr, eperm, xbuf, Sb, ybuf);
        // LN1
        stats_k<<<(N_NODES * DIM) / 1024, blk, 0, stream>>>(ybuf, stats);
        apply_k<<<(N_NODES * DIM) / 1024, blk, 0, stream>>>(ybuf, stats, g1 + bo, b1 + bo, xbuf);
        // FFN
        gemm_k<1,1,0,0><<<gff1, blk, 0, stream>>>(xbuf, W1 + w1o, c1 + b1o, nullptr, hb, N_NODES, DIM, DFF);
        gemm_k<1,0,1,0><<<gnode, blk, 0, stream>>>(hb, W2 + w1o, c2 + bo, xbuf, ybuf, N_NODES, DFF, DIM);
        stats_k<<<(N_NODES * DIM) / 1024, blk, 0, stream>>>(ybuf, stats + 2);
        float* xdst = (i == 2) ? (float*)d_out : xbuf;
        apply_k<<<(N_NODES * DIM) / 1024, blk, 0, stream>>>(ybuf, stats + 2, g2 + bo, b2 + bo, xdst);
    }
}

// Round 3
// 2044.624 us; speedup vs baseline: 2.9977x; 1.8974x over previous
//
#include <hip/hip_runtime.h>
#include <hip/hip_bf16.h>
#include <cstddef>

#define N_NODES 16000
#define N_EDGES 256000
#define DIM 256
#define HEADS 8
#define DFF 1024
#define LN_EPS 1e-5f
#define CNT ((float)((size_t)N_NODES * DIM))

typedef __attribute__((ext_vector_type(8))) short short8;
typedef __attribute__((ext_vector_type(4))) float floatx4;

__device__ __forceinline__ float bf2f(unsigned int s) {
    return __uint_as_float(s << 16);
}

// async global->LDS, 16B per lane (global_load_lds_dwordx4)
__device__ __forceinline__ void async16(const __hip_bfloat16* g, __hip_bfloat16* l) {
    __builtin_amdgcn_global_load_lds(
        (const __attribute__((address_space(1))) void*)g,
        (__attribute__((address_space(3))) void*)l, 16, 0, 0);
}

__device__ __forceinline__ void pack8(__hip_bfloat16* d, float4 a, float4 b) {
    union { short8 f; __hip_bfloat16 h[8]; } u;
    u.h[0] = __float2bfloat16(a.x); u.h[1] = __float2bfloat16(a.y);
    u.h[2] = __float2bfloat16(a.z); u.h[3] = __float2bfloat16(a.w);
    u.h[4] = __float2bfloat16(b.x); u.h[5] = __float2bfloat16(b.y);
    u.h[6] = __float2bfloat16(b.z); u.h[7] = __float2bfloat16(b.w);
    *(short8*)d = u.f;
}

// ---------------- bf16 MFMA GEMM: C[M,N] = A[M,K] @ Bt[N,K]^T  ----------------
// 128x128 tile, BK=32, 256 threads = 4 waves, each wave 64x64 via 4x4 frags of
// mfma_f32_16x16x32_bf16. ACVT=1: A is fp32, converted during staging.
// M%128==0, N%128==0, K%32==0.
template<int BIAS, int RELU, int RES, int OBF16, int ACVT>
__global__ __launch_bounds__(256) void mgemm_k(
    const void* __restrict__ Ap, const __hip_bfloat16* __restrict__ Bt,
    const float* __restrict__ bias, const float* __restrict__ res,
    void* __restrict__ C, int M, int K, int N)
{
    __shared__ __hip_bfloat16 As[128 * 32];   // [m][k] row-major, 8 KB
    __shared__ __hip_bfloat16 Bs[128 * 32];   // [n][k] row-major, 8 KB
    const int tid = threadIdx.x;
    const int lane = tid & 63, wv = tid >> 6;
    const int wm = (wv & 1) * 64, wn = (wv >> 1) * 64;
    const int row0 = blockIdx.y * 128, col0 = blockIdx.x * 128;
    const int lr = tid >> 2;            // 0..63: tile row (A) / tile n-row (B)
    const int lk = (tid & 3) * 8;       // k offset 0/8/16/24

    floatx4 acc[4][4];
    const floatx4 zf = {0.f, 0.f, 0.f, 0.f};
    #pragma unroll
    for (int i = 0; i < 4; i++)
        #pragma unroll
        for (int j = 0; j < 4; j++) acc[i][j] = zf;

    const int a_fo = (wm + (lane & 15)) * 32 + (lane >> 4) * 8;  // frag base offsets
    const int b_fo = (wn + (lane & 15)) * 32 + (lane >> 4) * 8;

    for (int k0 = 0; k0 < K; k0 += 32) {
        if (ACVT) {
            const float* A = (const float*)Ap;
            const float* p0 = A + (size_t)(row0 + lr) * K + k0 + lk;
            const float* p1 = A + (size_t)(row0 + lr + 64) * K + k0 + lk;
            float4 v0 = *(const float4*)(p0);
            float4 v1 = *(const float4*)(p0 + 4);
            float4 w0 = *(const float4*)(p1);
            float4 w1 = *(const float4*)(p1 + 4);
            pack8(As + tid * 8, v0, v1);
            pack8(As + 2048 + tid * 8, w0, w1);
        } else {
            const __hip_bfloat16* A = (const __hip_bfloat16*)Ap;
            async16(A + (size_t)(row0 + lr) * K + k0 + lk, As + tid * 8);
            async16(A + (size_t)(row0 + lr + 64) * K + k0 + lk, As + 2048 + tid * 8);
        }
        async16(Bt + (size_t)(col0 + lr) * K + k0 + lk, Bs + tid * 8);
        async16(Bt + (size_t)(col0 + lr + 64) * K + k0 + lk, Bs + 2048 + tid * 8);
        __syncthreads();
        short8 a[4], b[4];
        #pragma unroll
        for (int i = 0; i < 4; i++) {
            a[i] = *(const short8*)(As + a_fo + i * 16 * 32);
            b[i] = *(const short8*)(Bs + b_fo + i * 16 * 32);
        }
        #pragma unroll
        for (int i = 0; i < 4; i++)
            #pragma unroll
            for (int j = 0; j < 4; j++)
                acc[i][j] = __builtin_amdgcn_mfma_f32_16x16x32_bf16(a[i], b[j], acc[i][j], 0, 0, 0);
        __syncthreads();
    }
    // epilogue: D[m=(lane>>4)*4+r][n=lane&15] per 16x16 tile (m89/m91-verified)
    const int rbase = row0 + wm + (lane >> 4) * 4;
    const int cbase = col0 + wn + (lane & 15);
    #pragma unroll
    for (int j = 0; j < 4; j++) {
        const int c = cbase + j * 16;
        float bb = BIAS ? bias[c] : 0.0f;
        #pragma unroll
        for (int i = 0; i < 4; i++) {
            #pragma unroll
            for (int r = 0; r < 4; r++) {
                const int rr = rbase + i * 16 + r;
                float v = acc[i][j][r] + bb;
                if (RELU) v = fmaxf(v, 0.0f);
                if (RES)  v += res[(size_t)rr * N + c];
                if (OBF16) ((__hip_bfloat16*)C)[(size_t)rr * N + c] = __float2bfloat16(v);
                else       ((float*)C)[(size_t)rr * N + c] = v;
            }
        }
    }
}

// ---------------- weight transpose + bf16 convert: dst[C][R] = src[R][C] -------
__global__ __launch_bounds__(256) void tcvt_k(const float* __restrict__ src,
                                              __hip_bfloat16* __restrict__ dst,
                                              int R, int C)
{
    __shared__ float t[32][33];
    const int c0 = blockIdx.x * 32, r0 = blockIdx.y * 32;
    const int tx = threadIdx.x & 31, ty = threadIdx.x >> 5;   // 32 x 8
    #pragma unroll
    for (int j = 0; j < 32; j += 8)
        t[ty + j][tx] = src[(size_t)(r0 + ty + j) * C + c0 + tx];
    __syncthreads();
    #pragma unroll
    for (int j = 0; j < 32; j += 8)
        dst[(size_t)(c0 + ty + j) * R + r0 + tx] = __float2bfloat16(t[tx][ty + j]);
}

__global__ __launch_bounds__(256) void bcat_k(const float* __restrict__ bq,
                                              const float* __restrict__ bk,
                                              const float* __restrict__ bv,
                                              const float* __restrict__ bs,
                                              float* __restrict__ o)
{
    int t = blockIdx.x * 256 + threadIdx.x;   // 1024
    float v = (t < 256) ? bq[t] : (t < 512) ? bk[t - 256]
            : (t < 768) ? bv[t - 512] : bs[t - 768];
    o[t] = v;
}

// ---------------- CSR build: histogram -> scan -> scatter ----------------
__global__ __launch_bounds__(256) void hist_k(const int* __restrict__ dst, int* __restrict__ deg)
{
    int e = blockIdx.x * blockDim.x + threadIdx.x;
    if (e < N_EDGES) atomicAdd(&deg[dst[e]], 1);
}

__global__ __launch_bounds__(1024) void scan_k(const int* __restrict__ deg,
                                               int* __restrict__ rowptr,
                                               int* __restrict__ cursor)
{
    __shared__ int wsum[16];
    const int t = threadIdx.x;          // 16000 = 1000 threads x 16
    const int base = t * 16;
    int local[16];
    int s = 0;
    if (t < 1000) {
        #pragma unroll
        for (int j = 0; j < 16; j++) { local[j] = s; s += deg[base + j]; }
    }
    const int lane = t & 63, w = t >> 6;
    int v = s;
    #pragma unroll
    for (int off = 1; off < 64; off <<= 1) {
        int u = __shfl_up(v, off);
        if (lane >= off) v += u;
    }
    if (lane == 63) wsum[w] = v;
    __syncthreads();
    if (t == 0) {
        int r = 0;
        #pragma unroll
        for (int i = 0; i < 16; i++) { int u = wsum[i]; wsum[i] = r; r += u; }
    }
    __syncthreads();
    const int excl = v - s + wsum[w];
    if (t < 1000) {
        #pragma unroll
        for (int j = 0; j < 16; j++) {
            rowptr[base + j] = excl + local[j];
            cursor[base + j] = excl + local[j];
        }
        if (t == 999) rowptr[16000] = excl + s;
    }
}

__global__ __launch_bounds__(256) void scatter_k(const int* __restrict__ dst,
                                                 int* __restrict__ cursor,
                                                 int* __restrict__ eperm)
{
    int e = blockIdx.x * blockDim.x + threadIdx.x;
    if (e < N_EDGES) {
        int pos = atomicAdd(&cursor[dst[e]], 1);
        eperm[pos] = e;
    }
}

// ---------------- per-node attention aggregation (one wave per dst node) --------
// qkvs layout: [node][1024] = Q(0:256) K(256:512) V(512:768) S(768:1024)
__global__ __launch_bounds__(256) void node_agg_k(
    const float* __restrict__ qkvs, const __hip_bfloat16* __restrict__ Ep,
    const int* __restrict__ src, const float* __restrict__ x_dist,
    const int* __restrict__ rowptr, const int* __restrict__ eperm,
    const float* __restrict__ x, float* __restrict__ y)
{
    const int lane = threadIdx.x & 63;
    const int n = (blockIdx.x * blockDim.x + threadIdx.x) >> 6;
    if (n >= N_NODES) return;
    const float rsdh = 0.17677669529663687f;  // 1/sqrt(32)
    const float4 q = *(const float4*)(qkvs + (size_t)n * 1024 + lane * 4);
    float a0 = 0, a1 = 0, a2 = 0, a3 = 0, den = 0;
    const int beg = rowptr[n], end = rowptr[n + 1];
    int e = (beg < end) ? eperm[beg] : 0;
    int s = (beg < end) ? src[e] : 0;
    for (int i = beg; i < end; i++) {
        const int ecur = e, scur = s;
        if (i + 1 < end) { e = eperm[i + 1]; s = src[e]; }   // prefetch next gather idx
        const float4 kv = *(const float4*)(qkvs + (size_t)scur * 1024 + 256 + lane * 4);
        const float4 vv = *(const float4*)(qkvs + (size_t)scur * 1024 + 512 + lane * 4);
        const uint2 eb = *(const uint2*)(Ep + (size_t)ecur * DIM + lane * 4);
        const float invd = 1.0f / x_dist[ecur];
        const float e0 = bf2f(eb.x & 0xffffu), e1 = bf2f(eb.x >> 16);
        const float e2 = bf2f(eb.y & 0xffffu), e3 = bf2f(eb.y >> 16);
        float part = q.x * (kv.x + e0) + q.y * (kv.y + e1)
                   + q.z * (kv.z + e2) + q.w * (kv.w + e3);
        part += __shfl_xor(part, 1);
        part += __shfl_xor(part, 2);
        part += __shfl_xor(part, 4);   // 8 lanes of this head share the dot
        const float ex = __expf(part * invd * rsdh);
        den += ex;
        a0 = fmaf(vv.x + e0, ex, a0);
        a1 = fmaf(vv.y + e1, ex, a1);
        a2 = fmaf(vv.z + e2, ex, a2);
        a3 = fmaf(vv.w + e3, ex, a3);
    }
    const float dn = 1.0f / (den + 1e-16f);
    const float4 xr = *(const float4*)(x + (size_t)n * DIM + lane * 4);
    const float4 sr = *(const float4*)(qkvs + (size_t)n * 1024 + 768 + lane * 4);
    float4 out;
    out.x = xr.x + a0 * dn + sr.x;
    out.y = xr.y + a1 * dn + sr.y;
    out.z = xr.z + a2 * dn + sr.z;
    out.w = xr.w + a3 * dn + sr.w;
    *(float4*)(y + (size_t)n * DIM + lane * 4) = out;
}

// ---------------- LN stats / apply ----------------
__global__ __launch_bounds__(256) void stats_k(const float* __restrict__ y, float* __restrict__ stats)
{
    int idx = blockIdx.x * blockDim.x + threadIdx.x;  // float4 index
    float4 v = *(const float4*)(y + (size_t)idx * 4);
    float s = v.x + v.y + v.z + v.w;
    float ss = v.x * v.x + v.y * v.y + v.z * v.z + v.w * v.w;
    #pragma unroll
    for (int o = 32; o > 0; o >>= 1) {
        s  += __shfl_down(s, o);
        ss += __shfl_down(ss, o);
    }
    __shared__ float ls[4], lss[4];
    int w = threadIdx.x >> 6, ln = threadIdx.x & 63;
    if (ln == 0) { ls[w] = s; lss[w] = ss; }
    __syncthreads();
    if (threadIdx.x == 0) {
        atomicAdd(&stats[0], ls[0] + ls[1] + ls[2] + ls[3]);
        atomicAdd(&stats[1], lss[0] + lss[1] + lss[2] + lss[3]);
    }
}

__global__ __launch_bounds__(256) void apply_k(
    const float* __restrict__ y, const float* __restrict__ stats,
    const float* __restrict__ g, const float* __restrict__ b,
    float* __restrict__ xo)
{
    int idx = blockIdx.x * blockDim.x + threadIdx.x;  // float4 index
    float mu = stats[0] * (1.0f / CNT);
    float var = stats[1] * (1.0f / CNT) - mu * mu;
    float sc = 1.0f / (sqrtf(fmaxf(var, 0.0f)) + LN_EPS);
    int cb = (idx & 63) * 4;
    float4 v  = *(const float4*)(y + (size_t)idx * 4);
    float4 gv = *(const float4*)(g + cb);
    float4 bv = *(const float4*)(b + cb);
    float4 o;
    o.x = (v.x - mu) * sc * gv.x + bv.x;
    o.y = (v.y - mu) * sc * gv.y + bv.y;
    o.z = (v.z - mu) * sc * gv.z + bv.z;
    o.w = (v.w - mu) * sc * gv.w + bv.w;
    *(float4*)(xo + (size_t)idx * 4) = o;
}

extern "C" void kernel_launch(void* const* d_in, const int* in_sizes, int n_in,
                              void* d_out, int out_size, void* d_ws, size_t ws_size,
                              hipStream_t stream) {
    const float* x_in   = (const float*)d_in[0];
    const int*   ei     = (const int*)d_in[1];
    const int*   src    = ei;                 // edge_index[0]
    const int*   dstp   = ei + N_EDGES;       // edge_index[1]
    const float* x_edge = (const float*)d_in[2];
    const float* x_dist = (const float*)d_in[3];
    const float* Wq  = (const float*)d_in[4];
    const float* bq  = (const float*)d_in[5];
    const float* Wk  = (const float*)d_in[6];
    const float* bk  = (const float*)d_in[7];
    const float* Wv  = (const float*)d_in[8];
    const float* bv  = (const float*)d_in[9];
    const float* We  = (const float*)d_in[10];
    const float* Wsk = (const float*)d_in[11];
    const float* bsk = (const float*)d_in[12];
    const float* g1  = (const float*)d_in[13];
    const float* b1  = (const float*)d_in[14];
    const float* W1  = (const float*)d_in[15];
    const float* c1  = (const float*)d_in[16];
    const float* W2  = (const float*)d_in[17];
    const float* c2  = (const float*)d_in[18];
    const float* g2  = (const float*)d_in[19];
    const float* b2  = (const float*)d_in[20];

    // ---- workspace carve (~268 MB) ----
    char* p = (char*)d_ws;
    const size_t NB = (size_t)N_NODES * DIM * sizeof(float);   // 16.38 MB
    float* xbuf = (float*)p; p += NB;
    float* ybuf = (float*)p; p += NB;
    float* qkvs = (float*)p; p += (size_t)N_NODES * 1024 * sizeof(float);          // 65.5 MB
    __hip_bfloat16* hb16 = (__hip_bfloat16*)p; p += (size_t)N_NODES * 1024 * 2;    // 32.8 MB
    __hip_bfloat16* Ep   = (__hip_bfloat16*)p; p += (size_t)N_EDGES * DIM * 2;     // 131 MB
    __hip_bfloat16* WqkvsT = (__hip_bfloat16*)p; p += (size_t)3 * 1024 * 256 * 2;  // [3][1024][256]
    __hip_bfloat16* WeT    = (__hip_bfloat16*)p; p += (size_t)3 * 256 * 256 * 2;
    __hip_bfloat16* W1T    = (__hip_bfloat16*)p; p += (size_t)3 * 1024 * 256 * 2;
    __hip_bfloat16* W2T    = (__hip_bfloat16*)p; p += (size_t)3 * 256 * 1024 * 2;
    float* bqkvs = (float*)p; p += (size_t)3 * 1024 * sizeof(float);
    float* stats = (float*)p;  p += 32;
    int* deg     = (int*)p;    p += (size_t)N_NODES * sizeof(int);
    int* rowptr  = (int*)p;    p += (size_t)(N_NODES + 4) * sizeof(int);
    int* cursor  = (int*)p;    p += (size_t)N_NODES * sizeof(int);
    int* eperm   = (int*)p;    p += (size_t)N_EDGES * sizeof(int);

    hipMemcpyAsync(xbuf, x_in, NB, hipMemcpyDeviceToDevice, stream);

    const dim3 blk(256);

    // ---- CSR build (edge list constant across blocks) ----
    hipMemsetAsync(deg, 0, (size_t)N_NODES * sizeof(int), stream);
    hist_k<<<N_EDGES / 256, blk, 0, stream>>>(dstp, deg);
    scan_k<<<1, 1024, 0, stream>>>(deg, rowptr, cursor);
    scatter_k<<<N_EDGES / 256, blk, 0, stream>>>(dstp, cursor, eperm);

    // ---- weight prep: transpose + bf16 convert, all 3 blocks upfront ----
    for (int i = 0; i < 3; i++) {
        const float* wsrc[4] = {Wq, Wk, Wv, Wsk};
        for (int c = 0; c < 4; c++)
            tcvt_k<<<dim3(8, 8), blk, 0, stream>>>(wsrc[c] + (size_t)i * 65536,
                WqkvsT + (size_t)i * 262144 + (size_t)c * 65536, 256, 256);
        tcvt_k<<<dim3(8, 8), blk, 0, stream>>>(We + (size_t)i * 65536,
                WeT + (size_t)i * 65536, 256, 256);
        tcvt_k<<<dim3(32, 8), blk, 0, stream>>>(W1 + (size_t)i * 262144,
                W1T + (size_t)i * 262144, 256, 1024);
        tcvt_k<<<dim3(8, 32), blk, 0, stream>>>(W2 + (size_t)i * 262144,
                W2T + (size_t)i * 262144, 1024, 256);
        bcat_k<<<4, blk, 0, stream>>>(bq + (size_t)i * 256, bk + (size_t)i * 256,
                bv + (size_t)i * 256, bsk + (size_t)i * 256, bqkvs + (size_t)i * 1024);
    }

    for (int i = 0; i < 3; i++) {
        const size_t bo = (size_t)i * DIM;
        const size_t b1o = (size_t)i * DFF;

        hipMemsetAsync(stats, 0, 32, stream);

        // fused Q|K|V|S projection: [16000,256] x [256,1024] -> fp32
        mgemm_k<1,0,0,0,1><<<dim3(8, 125), blk, 0, stream>>>(
            xbuf, WqkvsT + (size_t)i * 262144, bqkvs + (size_t)i * 1024, nullptr,
            qkvs, N_NODES, DIM, 1024);
        // edge projection: [256000,256] x [256,256] -> bf16
        mgemm_k<0,0,0,1,1><<<dim3(2, 2000), blk, 0, stream>>>(
            x_edge, WeT + (size_t)i * 65536, nullptr, nullptr,
            Ep, N_EDGES, DIM, DIM);
        // attention aggregation fused with residual + skip -> ybuf
        node_agg_k<<<N_NODES / 4, blk, 0, stream>>>(qkvs, Ep, src, x_dist,
                                                    rowptr, eperm, xbuf, ybuf);
        // LN1
        stats_k<<<(N_NODES * DIM) / 1024, blk, 0, stream>>>(ybuf, stats);
        apply_k<<<(N_NODES * DIM) / 1024, blk, 0, stream>>>(ybuf, stats, g1 + bo, b1 + bo, xbuf);
        // FFN1: [16000,256] x [256,1024] + bias + relu -> bf16
        mgemm_k<1,1,0,1,1><<<dim3(8, 125), blk, 0, stream>>>(
            xbuf, W1T + (size_t)i * 262144, c1 + b1o, nullptr,
            hb16, N_NODES, DIM, DFF);
        // FFN2: [16000,1024] x [1024,256] + bias + residual -> fp32 ybuf
        mgemm_k<1,0,1,0,0><<<dim3(2, 125), blk, 0, stream>>>(
            hb16, W2T + (size_t)i * 262144, c2 + bo, xbuf,
            ybuf, N_NODES, DFF, DIM);
        // LN2
        stats_k<<<(N_NODES * DIM) / 1024, blk, 0, stream>>>(ybuf, stats + 2);
        float* xdst = (i == 2) ? (float*)d_out : xbuf;
        apply_k<<<(N_NODES * DIM) / 1024, blk, 0, stream>>>(ybuf, stats + 2, g2 + bo, b2 + bo, xdst);
    }
}

// Round 4
// 1603.201 us; speedup vs baseline: 3.8230x; 1.2753x over previous
//
#include <hip/hip_runtime.h>
#include <hip/hip_bf16.h>
#include <cstddef>

#define N_NODES 16000
#define N_EDGES 256000
#define DIM 256
#define HEADS 8
#define DFF 1024
#define LN_EPS 1e-5f
#define CNT ((float)((size_t)N_NODES * DIM))
#define RSDH 0.17677669529663687f

typedef __attribute__((ext_vector_type(8))) short short8;
typedef __attribute__((ext_vector_type(4))) float floatx4;

__device__ __forceinline__ float bf2f(unsigned int s) {
    return __uint_as_float(s << 16);
}

__device__ __forceinline__ float2 ln_ms(const float* __restrict__ s) {
    float mu = s[0] * (1.0f / CNT);
    float var = s[1] * (1.0f / CNT) - mu * mu;
    float2 r; r.x = mu; r.y = 1.0f / (sqrtf(fmaxf(var, 0.0f)) + LN_EPS);
    return r;
}

// async global->LDS, 16B per lane (global_load_lds_dwordx4)
__device__ __forceinline__ void async16(const __hip_bfloat16* g, __hip_bfloat16* l) {
    __builtin_amdgcn_global_load_lds(
        (const __attribute__((address_space(1))) void*)g,
        (__attribute__((address_space(3))) void*)l, 16, 0, 0);
}

__device__ __forceinline__ void pack8(__hip_bfloat16* d, float4 a, float4 b) {
    union { short8 f; __hip_bfloat16 h[8]; } u;
    u.h[0] = __float2bfloat16(a.x); u.h[1] = __float2bfloat16(a.y);
    u.h[2] = __float2bfloat16(a.z); u.h[3] = __float2bfloat16(a.w);
    u.h[4] = __float2bfloat16(b.x); u.h[5] = __float2bfloat16(b.y);
    u.h[6] = __float2bfloat16(b.z); u.h[7] = __float2bfloat16(b.w);
    *(short8*)d = u.f;
}

// ---------------- bf16 MFMA GEMM: C[M,N] = A[M,K] @ Bt[N,K]^T ----------------
// 128x128 tile, BK=32, 4 waves x (4x4) mfma_f32_16x16x32_bf16 frags.
// ACVT: A fp32, converted during staging (optional LN affine on read, lnA_*).
// RES:  residual read (optional LN affine on read, lnR_*).
// ostats: if non-null, block-reduced sum/sumsq of outputs -> atomicAdd.
template<int BIAS, int RELU, int RES, int OBF16, int ACVT>
__global__ __launch_bounds__(256) void mgemm_k(
    const void* __restrict__ Ap, const __hip_bfloat16* __restrict__ Bt,
    const float* __restrict__ bias, const float* __restrict__ res,
    void* __restrict__ C, int M, int K, int N,
    const float* __restrict__ lnA_s, const float* __restrict__ lnA_g,
    const float* __restrict__ lnA_b,
    const float* __restrict__ lnR_s, const float* __restrict__ lnR_g,
    const float* __restrict__ lnR_b,
    float* __restrict__ ostats)
{
    __shared__ __hip_bfloat16 As[128 * 32];   // [m][k] row-major, 8 KB
    __shared__ __hip_bfloat16 Bs[128 * 32];   // [n][k] row-major, 8 KB
    __shared__ float rs[8];
    const int tid = threadIdx.x;
    const int lane = tid & 63, wv = tid >> 6;
    const int wm = (wv & 1) * 64, wn = (wv >> 1) * 64;
    const int row0 = blockIdx.y * 128, col0 = blockIdx.x * 128;
    const int lr = tid >> 2;            // 0..63: tile row
    const int lk = (tid & 3) * 8;       // k offset 0/8/16/24

    float muA = 0.0f, scA = 1.0f;
    if (ACVT && lnA_s) { float2 t = ln_ms(lnA_s); muA = t.x; scA = t.y; }

    floatx4 acc[4][4];
    const floatx4 zf = {0.f, 0.f, 0.f, 0.f};
    #pragma unroll
    for (int i = 0; i < 4; i++)
        #pragma unroll
        for (int j = 0; j < 4; j++) acc[i][j] = zf;

    const int a_fo = (wm + (lane & 15)) * 32 + (lane >> 4) * 8;
    const int b_fo = (wn + (lane & 15)) * 32 + (lane >> 4) * 8;

    for (int k0 = 0; k0 < K; k0 += 32) {
        if (ACVT) {
            const float* A = (const float*)Ap;
            const float* p0 = A + (size_t)(row0 + lr) * K + k0 + lk;
            const float* p1 = A + (size_t)(row0 + lr + 64) * K + k0 + lk;
            float4 v0 = *(const float4*)(p0);
            float4 v1 = *(const float4*)(p0 + 4);
            float4 w0 = *(const float4*)(p1);
            float4 w1 = *(const float4*)(p1 + 4);
            if (lnA_s) {
                float4 ga = *(const float4*)(lnA_g + k0 + lk);
                float4 gb = *(const float4*)(lnA_g + k0 + lk + 4);
                float4 ba = *(const float4*)(lnA_b + k0 + lk);
                float4 bb = *(const float4*)(lnA_b + k0 + lk + 4);
                v0.x = (v0.x - muA) * scA * ga.x + ba.x;
                v0.y = (v0.y - muA) * scA * ga.y + ba.y;
                v0.z = (v0.z - muA) * scA * ga.z + ba.z;
                v0.w = (v0.w - muA) * scA * ga.w + ba.w;
                v1.x = (v1.x - muA) * scA * gb.x + bb.x;
                v1.y = (v1.y - muA) * scA * gb.y + bb.y;
                v1.z = (v1.z - muA) * scA * gb.z + bb.z;
                v1.w = (v1.w - muA) * scA * gb.w + bb.w;
                w0.x = (w0.x - muA) * scA * ga.x + ba.x;
                w0.y = (w0.y - muA) * scA * ga.y + ba.y;
                w0.z = (w0.z - muA) * scA * ga.z + ba.z;
                w0.w = (w0.w - muA) * scA * ga.w + ba.w;
                w1.x = (w1.x - muA) * scA * gb.x + bb.x;
                w1.y = (w1.y - muA) * scA * gb.y + bb.y;
                w1.z = (w1.z - muA) * scA * gb.z + bb.z;
                w1.w = (w1.w - muA) * scA * gb.w + bb.w;
            }
            pack8(As + tid * 8, v0, v1);
            pack8(As + 2048 + tid * 8, w0, w1);
        } else {
            const __hip_bfloat16* A = (const __hip_bfloat16*)Ap;
            async16(A + (size_t)(row0 + lr) * K + k0 + lk, As + tid * 8);
            async16(A + (size_t)(row0 + lr + 64) * K + k0 + lk, As + 2048 + tid * 8);
        }
        async16(Bt + (size_t)(col0 + lr) * K + k0 + lk, Bs + tid * 8);
        async16(Bt + (size_t)(col0 + lr + 64) * K + k0 + lk, Bs + 2048 + tid * 8);
        __syncthreads();
        short8 a[4], b[4];
        #pragma unroll
        for (int i = 0; i < 4; i++) {
            a[i] = *(const short8*)(As + a_fo + i * 16 * 32);
            b[i] = *(const short8*)(Bs + b_fo + i * 16 * 32);
        }
        #pragma unroll
        for (int i = 0; i < 4; i++)
            #pragma unroll
            for (int j = 0; j < 4; j++)
                acc[i][j] = __builtin_amdgcn_mfma_f32_16x16x32_bf16(a[i], b[j], acc[i][j], 0, 0, 0);
        __syncthreads();
    }
    // epilogue: D[m=(lane>>4)*4+r][n=lane&15] per 16x16 tile
    float muR = 0.0f, scR = 1.0f;
    if (RES && lnR_s) { float2 t = ln_ms(lnR_s); muR = t.x; scR = t.y; }
    const int rbase = row0 + wm + (lane >> 4) * 4;
    const int cbase = col0 + wn + (lane & 15);
    float s1 = 0.0f, s2 = 0.0f;
    #pragma unroll
    for (int j = 0; j < 4; j++) {
        const int c = cbase + j * 16;
        float bb = BIAS ? bias[c] : 0.0f;
        float gr = (RES && lnR_s) ? lnR_g[c] : 1.0f;
        float br = (RES && lnR_s) ? lnR_b[c] : 0.0f;
        #pragma unroll
        for (int i = 0; i < 4; i++) {
            #pragma unroll
            for (int r = 0; r < 4; r++) {
                const int rr = rbase + i * 16 + r;
                float v = acc[i][j][r] + bb;
                if (RELU) v = fmaxf(v, 0.0f);
                if (RES) {
                    float rv = res[(size_t)rr * N + c];
                    if (lnR_s) rv = (rv - muR) * scR * gr + br;
                    v += rv;
                }
                if (ostats) { s1 += v; s2 += v * v; }
                if (OBF16) ((__hip_bfloat16*)C)[(size_t)rr * N + c] = __float2bfloat16(v);
                else       ((float*)C)[(size_t)rr * N + c] = v;
            }
        }
    }
    if (ostats) {
        #pragma unroll
        for (int o = 32; o > 0; o >>= 1) {
            s1 += __shfl_down(s1, o);
            s2 += __shfl_down(s2, o);
        }
        if (lane == 0) { rs[wv] = s1; rs[4 + wv] = s2; }
        __syncthreads();
        if (tid == 0) {
            atomicAdd(&ostats[0], rs[0] + rs[1] + rs[2] + rs[3]);
            atomicAdd(&ostats[1], rs[4] + rs[5] + rs[6] + rs[7]);
        }
    }
}

// ---------------- weight transpose + bf16 convert: dst[C][R] = src[R][C] -------
__global__ __launch_bounds__(256) void tcvt_k(const float* __restrict__ src,
                                              __hip_bfloat16* __restrict__ dst,
                                              int R, int C)
{
    __shared__ float t[32][33];
    const int c0 = blockIdx.x * 32, r0 = blockIdx.y * 32;
    const int tx = threadIdx.x & 31, ty = threadIdx.x >> 5;   // 32 x 8
    #pragma unroll
    for (int j = 0; j < 32; j += 8)
        t[ty + j][tx] = src[(size_t)(r0 + ty + j) * C + c0 + tx];
    __syncthreads();
    #pragma unroll
    for (int j = 0; j < 32; j += 8)
        dst[(size_t)(c0 + ty + j) * R + r0 + tx] = __float2bfloat16(t[tx][ty + j]);
}

__global__ __launch_bounds__(256) void bcat_k(const float* __restrict__ bq,
                                              const float* __restrict__ bk,
                                              const float* __restrict__ bv,
                                              const float* __restrict__ bs,
                                              float* __restrict__ o)
{
    int t = blockIdx.x * 256 + threadIdx.x;   // 1024
    float v = (t < 256) ? bq[t] : (t < 512) ? bk[t - 256]
            : (t < 768) ? bv[t - 512] : bs[t - 768];
    o[t] = v;
}

// ---------------- CSR build ----------------
__global__ __launch_bounds__(256) void hist_k(const int* __restrict__ dst, int* __restrict__ deg)
{
    int e = blockIdx.x * blockDim.x + threadIdx.x;
    if (e < N_EDGES) atomicAdd(&deg[dst[e]], 1);
}

__global__ __launch_bounds__(1024) void scan_k(const int* __restrict__ deg,
                                               int* __restrict__ rowptr,
                                               int* __restrict__ cursor)
{
    __shared__ int wsum[16];
    const int t = threadIdx.x;          // 16000 = 1000 threads x 16
    const int base = t * 16;
    int local[16];
    int s = 0;
    if (t < 1000) {
        #pragma unroll
        for (int j = 0; j < 16; j++) { local[j] = s; s += deg[base + j]; }
    }
    const int lane = t & 63, w = t >> 6;
    int v = s;
    #pragma unroll
    for (int off = 1; off < 64; off <<= 1) {
        int u = __shfl_up(v, off);
        if (lane >= off) v += u;
    }
    if (lane == 63) wsum[w] = v;
    __syncthreads();
    if (t == 0) {
        int r = 0;
        #pragma unroll
        for (int i = 0; i < 16; i++) { int u = wsum[i]; wsum[i] = r; r += u; }
    }
    __syncthreads();
    const int excl = v - s + wsum[w];
    if (t < 1000) {
        #pragma unroll
        for (int j = 0; j < 16; j++) {
            rowptr[base + j] = excl + local[j];
            cursor[base + j] = excl + local[j];
        }
        if (t == 999) rowptr[16000] = excl + s;
    }
}

// scatter: also emit src and logit scale in CSR-permuted order
__global__ __launch_bounds__(256) void scatter_k(const int* __restrict__ dst,
                                                 const int* __restrict__ src,
                                                 const float* __restrict__ xd,
                                                 int* __restrict__ cursor,
                                                 int* __restrict__ eperm,
                                                 int* __restrict__ srcp,
                                                 float* __restrict__ scale)
{
    int e = blockIdx.x * blockDim.x + threadIdx.x;
    if (e < N_EDGES) {
        int pos = atomicAdd(&cursor[dst[e]], 1);
        eperm[pos] = e;
        srcp[pos] = src[e];
        scale[pos] = RSDH / xd[e];
    }
}

// gather x_edge rows into CSR order, bf16 (once per launch)
__global__ __launch_bounds__(256) void eprep_k(const float* __restrict__ xe,
                                               const int* __restrict__ eperm,
                                               __hip_bfloat16* __restrict__ xeb)
{
    const int r = blockIdx.x * 4 + (threadIdx.x >> 6);
    const int lane = threadIdx.x & 63;
    const int e = eperm[r];
    float4 v = *(const float4*)(xe + (size_t)e * DIM + lane * 4);
    union { short4 s; __hip_bfloat16 h[4]; } u;
    u.h[0] = __float2bfloat16(v.x); u.h[1] = __float2bfloat16(v.y);
    u.h[2] = __float2bfloat16(v.z); u.h[3] = __float2bfloat16(v.w);
    *(short4*)(xeb + (size_t)r * DIM + lane * 4) = u.s;
}

// ---------------- per-node attention aggregation (one wave per dst node) --------
// Ep/srcp/scale are in CSR order -> fully sequential streams. qkvs gather is
// L3-resident. Fused: x-residual (optional LN-on-read) + skip + LN1 stats.
__global__ __launch_bounds__(256) void node_agg_k(
    const float* __restrict__ qkvs, const __hip_bfloat16* __restrict__ Ep,
    const int* __restrict__ srcp, const float* __restrict__ scale,
    const int* __restrict__ rowptr,
    const float* __restrict__ xsrc, const float* __restrict__ lnx_s,
    const float* __restrict__ lnx_g, const float* __restrict__ lnx_b,
    float* __restrict__ y, float* __restrict__ ostats)
{
    __shared__ float rs[8];
    const int lane = threadIdx.x & 63;
    const int wv = threadIdx.x >> 6;
    const int n = blockIdx.x * 4 + wv;          // grid = N_NODES/4 exactly
    const float4 q = *(const float4*)(qkvs + (size_t)n * 1024 + lane * 4);
    float a0 = 0, a1 = 0, a2 = 0, a3 = 0, den = 0;
    const int beg = rowptr[n], end = rowptr[n + 1];
    int s = (beg < end) ? srcp[beg] : 0;
    for (int i = beg; i < end; i++) {
        const int scur = s;
        if (i + 1 < end) s = srcp[i + 1];       // break dependency for next gather
        const float sc = scale[i];
        const float4 kv = *(const float4*)(qkvs + (size_t)scur * 1024 + 256 + lane * 4);
        const float4 vv = *(const float4*)(qkvs + (size_t)scur * 1024 + 512 + lane * 4);
        const uint2 eb = *(const uint2*)(Ep + (size_t)i * DIM + lane * 4);
        const float e0 = bf2f(eb.x & 0xffffu), e1 = bf2f(eb.x >> 16);
        const float e2 = bf2f(eb.y & 0xffffu), e3 = bf2f(eb.y >> 16);
        float part = q.x * (kv.x + e0) + q.y * (kv.y + e1)
                   + q.z * (kv.z + e2) + q.w * (kv.w + e3);
        part += __shfl_xor(part, 1);
        part += __shfl_xor(part, 2);
        part += __shfl_xor(part, 4);   // 8 lanes of this head share the dot
        const float ex = __expf(part * sc);
        den += ex;
        a0 = fmaf(vv.x + e0, ex, a0);
        a1 = fmaf(vv.y + e1, ex, a1);
        a2 = fmaf(vv.z + e2, ex, a2);
        a3 = fmaf(vv.w + e3, ex, a3);
    }
    const float dn = 1.0f / (den + 1e-16f);
    const size_t o = (size_t)n * DIM + lane * 4;
    float4 xr = *(const float4*)(xsrc + o);
    if (lnx_s) {
        float2 t = ln_ms(lnx_s);
        const float4 g4 = *(const float4*)(lnx_g + lane * 4);
        const float4 b4 = *(const float4*)(lnx_b + lane * 4);
        xr.x = (xr.x - t.x) * t.y * g4.x + b4.x;
        xr.y = (xr.y - t.x) * t.y * g4.y + b4.y;
        xr.z = (xr.z - t.x) * t.y * g4.z + b4.z;
        xr.w = (xr.w - t.x) * t.y * g4.w + b4.w;
    }
    const float4 sr = *(const float4*)(qkvs + (size_t)n * 1024 + 768 + lane * 4);
    float4 out;
    out.x = xr.x + a0 * dn + sr.x;
    out.y = xr.y + a1 * dn + sr.y;
    out.z = xr.z + a2 * dn + sr.z;
    out.w = xr.w + a3 * dn + sr.w;
    *(float4*)(y + o) = out;
    // LN1 stats
    float s1 = out.x + out.y + out.z + out.w;
    float s2 = out.x * out.x + out.y * out.y + out.z * out.z + out.w * out.w;
    #pragma unroll
    for (int of = 32; of > 0; of >>= 1) {
        s1 += __shfl_down(s1, of);
        s2 += __shfl_down(s2, of);
    }
    if (lane == 0) { rs[wv] = s1; rs[4 + wv] = s2; }
    __syncthreads();
    if (threadIdx.x == 0) {
        atomicAdd(&ostats[0], rs[0] + rs[1] + rs[2] + rs[3]);
        atomicAdd(&ostats[1], rs[4] + rs[5] + rs[6] + rs[7]);
    }
}

// ---------------- final LN apply (only for d_out) ----------------
__global__ __launch_bounds__(256) void apply_k(
    const float* __restrict__ y, const float* __restrict__ stats,
    const float* __restrict__ g, const float* __restrict__ b,
    float* __restrict__ xo)
{
    int idx = blockIdx.x * blockDim.x + threadIdx.x;  // float4 index
    float2 t = ln_ms(stats);
    int cb = (idx & 63) * 4;
    float4 v  = *(const float4*)(y + (size_t)idx * 4);
    float4 gv = *(const float4*)(g + cb);
    float4 bv = *(const float4*)(b + cb);
    float4 o;
    o.x = (v.x - t.x) * t.y * gv.x + bv.x;
    o.y = (v.y - t.x) * t.y * gv.y + bv.y;
    o.z = (v.z - t.x) * t.y * gv.z + bv.z;
    o.w = (v.w - t.x) * t.y * gv.w + bv.w;
    *(float4*)(xo + (size_t)idx * 4) = o;
}

extern "C" void kernel_launch(void* const* d_in, const int* in_sizes, int n_in,
                              void* d_out, int out_size, void* d_ws, size_t ws_size,
                              hipStream_t stream) {
    const float* x_in   = (const float*)d_in[0];
    const int*   ei     = (const int*)d_in[1];
    const int*   src    = ei;                 // edge_index[0]
    const int*   dstp   = ei + N_EDGES;       // edge_index[1]
    const float* x_edge = (const float*)d_in[2];
    const float* x_dist = (const float*)d_in[3];
    const float* Wq  = (const float*)d_in[4];
    const float* bq  = (const float*)d_in[5];
    const float* Wk  = (const float*)d_in[6];
    const float* bk  = (const float*)d_in[7];
    const float* Wv  = (const float*)d_in[8];
    const float* bv  = (const float*)d_in[9];
    const float* We  = (const float*)d_in[10];
    const float* Wsk = (const float*)d_in[11];
    const float* bsk = (const float*)d_in[12];
    const float* g1  = (const float*)d_in[13];
    const float* b1  = (const float*)d_in[14];
    const float* W1  = (const float*)d_in[15];
    const float* c1  = (const float*)d_in[16];
    const float* W2  = (const float*)d_in[17];
    const float* c2  = (const float*)d_in[18];
    const float* g2  = (const float*)d_in[19];
    const float* b2  = (const float*)d_in[20];

    // ---- workspace carve ----
    char* p = (char*)d_ws;
    float* ybuf = (float*)p; p += (size_t)N_NODES * DIM * sizeof(float);           // 16.4 MB
    float* qkvs = (float*)p; p += (size_t)N_NODES * 1024 * sizeof(float);          // 65.5 MB
    __hip_bfloat16* hb16 = (__hip_bfloat16*)p; p += (size_t)N_NODES * 1024 * 2;    // 32.8 MB
    __hip_bfloat16* Ep   = (__hip_bfloat16*)p; p += (size_t)N_EDGES * DIM * 2;     // 131 MB
    __hip_bfloat16* xeb  = (__hip_bfloat16*)p; p += (size_t)N_EDGES * DIM * 2;     // 131 MB
    __hip_bfloat16* WqkvsT = (__hip_bfloat16*)p; p += (size_t)3 * 1024 * 256 * 2;
    __hip_bfloat16* WeT    = (__hip_bfloat16*)p; p += (size_t)3 * 256 * 256 * 2;
    __hip_bfloat16* W1T    = (__hip_bfloat16*)p; p += (size_t)3 * 1024 * 256 * 2;
    __hip_bfloat16* W2T    = (__hip_bfloat16*)p; p += (size_t)3 * 256 * 1024 * 2;
    float* bqkvs = (float*)p; p += (size_t)3 * 1024 * sizeof(float);
    float* stats = (float*)p;  p += 64;                       // [block][ln1_s,ln1_ss,ln2_s,ln2_ss]
    int* deg     = (int*)p;    p += (size_t)N_NODES * sizeof(int);
    int* rowptr  = (int*)p;    p += (size_t)(N_NODES + 4) * sizeof(int);
    int* cursor  = (int*)p;    p += (size_t)N_NODES * sizeof(int);
    int* eperm   = (int*)p;    p += (size_t)N_EDGES * sizeof(int);
    int* srcp    = (int*)p;    p += (size_t)N_EDGES * sizeof(int);
    float* scale = (float*)p;  p += (size_t)N_EDGES * sizeof(float);

    const dim3 blk(256);

    // ---- CSR build (edge list constant across blocks) ----
    hipMemsetAsync(deg, 0, (size_t)N_NODES * sizeof(int), stream);
    hipMemsetAsync(stats, 0, 48, stream);
    hist_k<<<N_EDGES / 256, blk, 0, stream>>>(dstp, deg);
    scan_k<<<1, 1024, 0, stream>>>(deg, rowptr, cursor);
    scatter_k<<<N_EDGES / 256, blk, 0, stream>>>(dstp, src, x_dist, cursor, eperm, srcp, scale);
    eprep_k<<<N_EDGES / 4, blk, 0, stream>>>(x_edge, eperm, xeb);

    // ---- weight prep: transpose + bf16 convert ----
    for (int i = 0; i < 3; i++) {
        const float* wsrc[4] = {Wq, Wk, Wv, Wsk};
        for (int c = 0; c < 4; c++)
            tcvt_k<<<dim3(8, 8), blk, 0, stream>>>(wsrc[c] + (size_t)i * 65536,
                WqkvsT + (size_t)i * 262144 + (size_t)c * 65536, 256, 256);
        tcvt_k<<<dim3(8, 8), blk, 0, stream>>>(We + (size_t)i * 65536,
                WeT + (size_t)i * 65536, 256, 256);
        tcvt_k<<<dim3(32, 8), blk, 0, stream>>>(W1 + (size_t)i * 262144,
                W1T + (size_t)i * 262144, 256, 1024);
        tcvt_k<<<dim3(8, 32), blk, 0, stream>>>(W2 + (size_t)i * 262144,
                W2T + (size_t)i * 262144, 1024, 256);
        bcat_k<<<4, blk, 0, stream>>>(bq + (size_t)i * 256, bk + (size_t)i * 256,
                bv + (size_t)i * 256, bsk + (size_t)i * 256, bqkvs + (size_t)i * 1024);
    }

    for (int i = 0; i < 3; i++) {
        const size_t bo = (size_t)i * DIM;
        const size_t b1o = (size_t)i * DFF;
        float* ln1 = stats + (size_t)i * 4;
        float* ln2 = stats + (size_t)i * 4 + 2;
        // LN2 of previous block, applied on-read to x
        const float* pls = (i == 0) ? nullptr : stats + (size_t)(i - 1) * 4 + 2;
        const float* plg = (i == 0) ? nullptr : g2 + (size_t)(i - 1) * 256;
        const float* plb = (i == 0) ? nullptr : b2 + (size_t)(i - 1) * 256;
        const float* xsrc = (i == 0) ? x_in : ybuf;

        // fused Q|K|V|S projection: LN(x) [16000,256] x [256,1024] -> fp32
        mgemm_k<1,0,0,0,1><<<dim3(8, 125), blk, 0, stream>>>(
            xsrc, WqkvsT + (size_t)i * 262144, bqkvs + (size_t)i * 1024, nullptr,
            qkvs, N_NODES, DIM, 1024, pls, plg, plb, nullptr, nullptr, nullptr, nullptr);
        // edge projection (CSR-ordered bf16 A): [256000,256] x [256,256] -> bf16
        mgemm_k<0,0,0,1,0><<<dim3(2, 2000), blk, 0, stream>>>(
            xeb, WeT + (size_t)i * 65536, nullptr, nullptr,
            Ep, N_EDGES, DIM, DIM, nullptr, nullptr, nullptr, nullptr, nullptr, nullptr, nullptr);
        // attention aggregation + residual + skip + LN1 stats -> ybuf
        node_agg_k<<<N_NODES / 4, blk, 0, stream>>>(qkvs, Ep, srcp, scale, rowptr,
                                                    xsrc, pls, plg, plb, ybuf, ln1);
        // FFN1: LN1(y) x W1 + bias + relu -> bf16
        mgemm_k<1,1,0,1,1><<<dim3(8, 125), blk, 0, stream>>>(
            ybuf, W1T + (size_t)i * 262144, c1 + b1o, nullptr,
            hb16, N_NODES, DIM, DFF, ln1, g1 + bo, b1 + bo, nullptr, nullptr, nullptr, nullptr);
        // FFN2: h x W2 + bias + LN1(y) residual -> ybuf (in-place) + LN2 stats
        mgemm_k<1,0,1,0,0><<<dim3(2, 125), blk, 0, stream>>>(
            hb16, W2T + (size_t)i * 262144, c2 + bo, ybuf,
            ybuf, N_NODES, DFF, DIM, nullptr, nullptr, nullptr, ln1, g1 + bo, b1 + bo, ln2);
        if (i == 2)
            apply_k<<<(N_NODES * DIM) / 1024, blk, 0, stream>>>(
                ybuf, ln2, g2 + bo, b2 + bo, (float*)d_out);
    }
}